// Round 1
// baseline (895.841 us; speedup 1.0000x reference)
//
#include <hip/hip_runtime.h>
#include <hip/hip_bf16.h>

#define N_NODES 50000
#define N_EDGES 800000
#define FEAT 64
#define NRELS 8

// ---------------------------------------------------------------------------
// Kernel 1: in-degree via float atomics (exact for counts < 2^24)
// ---------------------------------------------------------------------------
__global__ void deg_kernel(const int* __restrict__ dst, float* __restrict__ deg, int E) {
    int e = blockIdx.x * blockDim.x + threadIdx.x;
    if (e < E) atomicAdd(deg + dst[e], 1.0f);
}

// ---------------------------------------------------------------------------
// Kernel 2: hw[r][n][f] = sum_d feat[n][d] * W[r][d][f]
// Block = 256 threads, computes a 64-node x 64-feat tile for one relation.
// W tile + padded feat tile staged in LDS; float4 accumulate per thread.
// ---------------------------------------------------------------------------
__global__ void hw_kernel(const float* __restrict__ feat, const float* __restrict__ W,
                          float* __restrict__ hw, int N) {
    __shared__ float Wl[64 * 64];      // [d][f]
    __shared__ float Fl[64 * 65];      // [n][d], +1 pad to break bank aliasing
    const int r  = blockIdx.y;
    const int n0 = blockIdx.x * 64;
    const int t  = threadIdx.x;

    // Load W_r (4096 floats) via float4, straight copy.
    const float4* W4  = (const float4*)(W + (size_t)r * 4096);
    float4*       Wl4 = (float4*)Wl;
#pragma unroll
    for (int i = 0; i < 4; i++) Wl4[t + 256 * i] = W4[t + 256 * i];

    // Load feat tile (64 nodes x 64 d), scalar coalesced, padded stride 65.
#pragma unroll
    for (int i = 0; i < 16; i++) {
        int idx = t + 256 * i;
        int n = idx >> 6, d = idx & 63;
        int gn = n0 + n;
        Fl[n * 65 + d] = (gn < N) ? feat[(size_t)gn * 64 + d] : 0.0f;
    }
    __syncthreads();

    const int q  = t & 15;   // float4 column group: f = q*4..q*4+3
    const int nl = t >> 4;   // node sub-index 0..15
#pragma unroll
    for (int pass = 0; pass < 4; pass++) {
        int n = nl + pass * 16;
        float4 acc = make_float4(0.f, 0.f, 0.f, 0.f);
#pragma unroll
        for (int d = 0; d < 64; d++) {
            float  fv = Fl[n * 65 + d];
            float4 wv = Wl4[d * 16 + q];
            acc.x += fv * wv.x; acc.y += fv * wv.y;
            acc.z += fv * wv.z; acc.w += fv * wv.w;
        }
        int gn = n0 + n;
        if (gn < N)
            ((float4*)hw)[((size_t)r * N + gn) * 16 + q] = acc;
    }
}

// ---------------------------------------------------------------------------
// Kernel 3: per-edge scatter: out[dst] += hw[etype][src]   (divide by deg later)
// 16 threads per edge, float4 gather, 4 scalar atomics each.
// ---------------------------------------------------------------------------
__global__ void scatter_kernel(const int* __restrict__ src, const int* __restrict__ dst,
                               const int* __restrict__ et, const float* __restrict__ hw,
                               float* __restrict__ out, int E, int N) {
    int t = blockIdx.x * blockDim.x + threadIdx.x;
    int e = t >> 4, q = t & 15;
    if (e >= E) return;
    int s = src[e], dd = dst[e], r = et[e];
    float4 v = ((const float4*)hw)[((size_t)r * N + s) * 16 + q];
    float* o = out + (size_t)dd * 64 + q * 4;
    atomicAdd(o + 0, v.x);
    atomicAdd(o + 1, v.y);
    atomicAdd(o + 2, v.z);
    atomicAdd(o + 3, v.w);
}

// ---------------------------------------------------------------------------
// Kernel 3-alt (small-workspace fallback): on-the-fly transform, wave per edge.
// ---------------------------------------------------------------------------
__global__ void otf_kernel(const int* __restrict__ src, const int* __restrict__ dst,
                           const int* __restrict__ et, const float* __restrict__ feat,
                           const float* __restrict__ W, float* __restrict__ out, int E) {
    int wid = (blockIdx.x * blockDim.x + threadIdx.x) >> 6;
    int l = threadIdx.x & 63;
    if (wid >= E) return;
    int s = src[wid], dd = dst[wid], r = et[wid];
    float fv = feat[(size_t)s * 64 + l];
    const float* Wr = W + (size_t)r * 4096;
    float acc = 0.f;
#pragma unroll
    for (int d = 0; d < 64; d++) {
        float a = __shfl(fv, d);
        acc += a * Wr[d * 64 + l];
    }
    atomicAdd(out + (size_t)dd * 64 + l, acc);
}

// ---------------------------------------------------------------------------
// Kernel 4: epilogue. out currently holds raw message sums.
// out = deg>0 ? relu(0.2*feat + 0.8*sum/deg) : feat
// ---------------------------------------------------------------------------
__global__ void final_kernel(const float* __restrict__ feat, const float* __restrict__ deg,
                             float* __restrict__ out, int N) {
    int i = blockIdx.x * blockDim.x + threadIdx.x;   // over N*16 float4s
    if (i >= N * 16) return;
    int n = i >> 4;
    float d = deg[n];
    float4 f = ((const float4*)feat)[i];
    float4 m = ((float4*)out)[i];
    float4 res;
    if (d > 0.f) {
        float inv = 0.8f / d;
        res.x = fmaxf(0.2f * f.x + m.x * inv, 0.f);
        res.y = fmaxf(0.2f * f.y + m.y * inv, 0.f);
        res.z = fmaxf(0.2f * f.z + m.z * inv, 0.f);
        res.w = fmaxf(0.2f * f.w + m.w * inv, 0.f);
    } else {
        res = f;
    }
    ((float4*)out)[i] = res;
}

extern "C" void kernel_launch(void* const* d_in, const int* in_sizes, int n_in,
                              void* d_out, int out_size, void* d_ws, size_t ws_size,
                              hipStream_t stream) {
    const float* feat = (const float*)d_in[0];   // [N, 64]
    const float* W    = (const float*)d_in[1];   // [8, 64, 64]
    const int*   src  = (const int*)d_in[2];     // [E]
    const int*   dst  = (const int*)d_in[3];     // [E]
    const int*   et   = (const int*)d_in[4];     // [E]
    float* out = (float*)d_out;                  // [N, 64]

    const int N = N_NODES, E = N_EDGES;

    // Workspace layout: [deg: N floats (256B-aligned)] [hw: 8*N*64 floats]
    float* deg = (float*)d_ws;
    size_t deg_bytes = (((size_t)N * 4) + 255) & ~(size_t)255;
    float* hw = (float*)((char*)d_ws + deg_bytes);
    size_t need = deg_bytes + (size_t)NRELS * N * FEAT * 4;

    // Zero accumulators (harness poisons d_out/d_ws with 0xAA each call).
    hipMemsetAsync(out, 0, (size_t)N * FEAT * 4, stream);
    hipMemsetAsync(deg, 0, (size_t)N * 4, stream);

    deg_kernel<<<(E + 255) / 256, 256, 0, stream>>>(dst, deg, E);

    if (ws_size >= need) {
        hw_kernel<<<dim3((N + 63) / 64, NRELS), 256, 0, stream>>>(feat, W, hw, N);
        scatter_kernel<<<((size_t)E * 16 + 255) / 256, 256, 0, stream>>>(src, dst, et, hw, out, E, N);
    } else {
        // 4 edges (waves) per 256-thread block
        otf_kernel<<<(E + 3) / 4, 256, 0, stream>>>(src, dst, et, feat, W, out, E);
    }

    final_kernel<<<(N * 16 + 255) / 256, 256, 0, stream>>>(feat, deg, out, N);
}

// Round 2
// 428.266 us; speedup vs baseline: 2.0918x; 2.0918x over previous
//
#include <hip/hip_runtime.h>
#include <hip/hip_bf16.h>

#define N_NODES 50000
#define N_EDGES 800000
#define FEAT 64
#define NRELS 8

static __host__ __device__ inline size_t align256(size_t x) { return (x + 255) & ~(size_t)255; }

// ---------------------------------------------------------------------------
// Kernel 1: int histogram of dst -> cnt (in-degree)
// ---------------------------------------------------------------------------
__global__ void hist_kernel(const int* __restrict__ dst, int* __restrict__ cnt, int E) {
    int e = blockIdx.x * blockDim.x + threadIdx.x;
    if (e < E) atomicAdd(cnt + dst[e], 1);
}

// ---------------------------------------------------------------------------
// Kernel 2: single-block exclusive scan of cnt[N] -> off[N+1], and cursor copy.
// 1024 threads, ITEMS=ceil(N/1024) sequential items per thread.
// ---------------------------------------------------------------------------
__global__ void scan_kernel(const int* __restrict__ cnt, int* __restrict__ off,
                            int* __restrict__ cur, int N) {
    __shared__ int sums[1024];
    const int t = threadIdx.x;
    const int ITEMS = (N + 1023) / 1024;
    const int base = t * ITEMS;
    int s = 0;
    for (int j = 0; j < ITEMS; j++) {
        int i = base + j;
        if (i < N) s += cnt[i];
    }
    sums[t] = s;
    __syncthreads();
    // Hillis-Steele inclusive scan over 1024 thread sums
    for (int o = 1; o < 1024; o <<= 1) {
        int v = (t >= o) ? sums[t - o] : 0;
        __syncthreads();
        sums[t] += v;
        __syncthreads();
    }
    int run = sums[t] - s;   // exclusive prefix for this thread's chunk
    for (int j = 0; j < ITEMS; j++) {
        int i = base + j;
        if (i < N) {
            off[i] = run;
            cur[i] = run;
            run += cnt[i];
        }
    }
    if (t == 1023) off[N] = sums[1023];
}

// ---------------------------------------------------------------------------
// Kernel 3: CSR fill (counting-sort scatter of edge ids)
// ---------------------------------------------------------------------------
__global__ void fill_kernel(const int* __restrict__ dst, int* __restrict__ cur,
                            int* __restrict__ eid, int E) {
    int e = blockIdx.x * blockDim.x + threadIdx.x;
    if (e < E) {
        int pos = atomicAdd(cur + dst[e], 1);
        eid[pos] = e;
    }
}

// ---------------------------------------------------------------------------
// Kernel 4: hw[r][n][f] = sum_d feat[n][d] * W[r][d][f]  (unchanged from R0)
// ---------------------------------------------------------------------------
__global__ void hw_kernel(const float* __restrict__ feat, const float* __restrict__ W,
                          float* __restrict__ hw, int N) {
    __shared__ float Wl[64 * 64];      // [d][f]
    __shared__ float Fl[64 * 65];      // [n][d], +1 pad
    const int r  = blockIdx.y;
    const int n0 = blockIdx.x * 64;
    const int t  = threadIdx.x;

    const float4* W4  = (const float4*)(W + (size_t)r * 4096);
    float4*       Wl4 = (float4*)Wl;
#pragma unroll
    for (int i = 0; i < 4; i++) Wl4[t + 256 * i] = W4[t + 256 * i];

#pragma unroll
    for (int i = 0; i < 16; i++) {
        int idx = t + 256 * i;
        int n = idx >> 6, d = idx & 63;
        int gn = n0 + n;
        Fl[n * 65 + d] = (gn < N) ? feat[(size_t)gn * 64 + d] : 0.0f;
    }
    __syncthreads();

    const int q  = t & 15;
    const int nl = t >> 4;
#pragma unroll
    for (int pass = 0; pass < 4; pass++) {
        int n = nl + pass * 16;
        float4 acc = make_float4(0.f, 0.f, 0.f, 0.f);
#pragma unroll
        for (int d = 0; d < 64; d++) {
            float  fv = Fl[n * 65 + d];
            float4 wv = Wl4[d * 16 + q];
            acc.x += fv * wv.x; acc.y += fv * wv.y;
            acc.z += fv * wv.z; acc.w += fv * wv.w;
        }
        int gn = n0 + n;
        if (gn < N)
            ((float4*)hw)[((size_t)r * N + gn) * 16 + q] = acc;
    }
}

// ---------------------------------------------------------------------------
// Kernel 5: fused gather-reduce + epilogue. One wave per dst node.
// Lane layout: g = lane>>4 (edge subgroup, 4 edges in flight), q = lane&15
// (float4 slice of the 64-dim feature). Cross-group shfl_xor reduce at end.
// out = deg>0 ? relu(0.2*f + 0.8*sum/deg) : f
// ---------------------------------------------------------------------------
__global__ void reduce_kernel(const int* __restrict__ off, const int* __restrict__ eid,
                              const int* __restrict__ src, const int* __restrict__ et,
                              const float* __restrict__ hw, const float* __restrict__ feat,
                              float* __restrict__ out, int N) {
    const int node = blockIdx.x * 4 + (threadIdx.x >> 6);
    if (node >= N) return;
    const int lane = threadIdx.x & 63;
    const int g = lane >> 4, q = lane & 15;

    const int b = off[node], e = off[node + 1];
    const int deg = e - b;

    float ax = 0.f, ay = 0.f, az = 0.f, aw = 0.f;
    for (int i = b + g; i < e; i += 4) {
        int edge = eid[i];
        int s = src[edge], r = et[edge];
        float4 v = ((const float4*)hw)[((size_t)r * N + s) * 16 + q];
        ax += v.x; ay += v.y; az += v.z; aw += v.w;
    }
    // reduce the 4 edge-subgroups (lanes q, q+16, q+32, q+48)
    ax += __shfl_xor(ax, 16); ay += __shfl_xor(ay, 16);
    az += __shfl_xor(az, 16); aw += __shfl_xor(aw, 16);
    ax += __shfl_xor(ax, 32); ay += __shfl_xor(ay, 32);
    az += __shfl_xor(az, 32); aw += __shfl_xor(aw, 32);

    float4 f = ((const float4*)feat)[(size_t)node * 16 + q];
    float4 res;
    if (deg > 0) {
        float inv = 0.8f / (float)deg;
        res.x = fmaxf(0.2f * f.x + ax * inv, 0.f);
        res.y = fmaxf(0.2f * f.y + ay * inv, 0.f);
        res.z = fmaxf(0.2f * f.z + az * inv, 0.f);
        res.w = fmaxf(0.2f * f.w + aw * inv, 0.f);
    } else {
        res = f;
    }
    if (g == 0)
        ((float4*)out)[(size_t)node * 16 + q] = res;
}

// ---------------------------------------------------------------------------
// Fallback kernels (small workspace): R0 atomic-scatter path
// ---------------------------------------------------------------------------
__global__ void degf_kernel(const int* __restrict__ dst, float* __restrict__ deg, int E) {
    int e = blockIdx.x * blockDim.x + threadIdx.x;
    if (e < E) atomicAdd(deg + dst[e], 1.0f);
}

__global__ void scatter_kernel(const int* __restrict__ src, const int* __restrict__ dst,
                               const int* __restrict__ et, const float* __restrict__ hw,
                               float* __restrict__ out, int E, int N) {
    int t = blockIdx.x * blockDim.x + threadIdx.x;
    int e = t >> 4, q = t & 15;
    if (e >= E) return;
    int s = src[e], dd = dst[e], r = et[e];
    float4 v = ((const float4*)hw)[((size_t)r * N + s) * 16 + q];
    float* o = out + (size_t)dd * 64 + q * 4;
    atomicAdd(o + 0, v.x);
    atomicAdd(o + 1, v.y);
    atomicAdd(o + 2, v.z);
    atomicAdd(o + 3, v.w);
}

__global__ void otf_kernel(const int* __restrict__ src, const int* __restrict__ dst,
                           const int* __restrict__ et, const float* __restrict__ feat,
                           const float* __restrict__ W, float* __restrict__ out, int E) {
    int wid = (blockIdx.x * blockDim.x + threadIdx.x) >> 6;
    int l = threadIdx.x & 63;
    if (wid >= E) return;
    int s = src[wid], dd = dst[wid], r = et[wid];
    float fv = feat[(size_t)s * 64 + l];
    const float* Wr = W + (size_t)r * 4096;
    float acc = 0.f;
#pragma unroll
    for (int d = 0; d < 64; d++) {
        float a = __shfl(fv, d);
        acc += a * Wr[d * 64 + l];
    }
    atomicAdd(out + (size_t)dd * 64 + l, acc);
}

__global__ void final_kernel(const float* __restrict__ feat, const float* __restrict__ deg,
                             float* __restrict__ out, int N) {
    int i = blockIdx.x * blockDim.x + threadIdx.x;
    if (i >= N * 16) return;
    int n = i >> 4;
    float d = deg[n];
    float4 f = ((const float4*)feat)[i];
    float4 m = ((float4*)out)[i];
    float4 res;
    if (d > 0.f) {
        float inv = 0.8f / d;
        res.x = fmaxf(0.2f * f.x + m.x * inv, 0.f);
        res.y = fmaxf(0.2f * f.y + m.y * inv, 0.f);
        res.z = fmaxf(0.2f * f.z + m.z * inv, 0.f);
        res.w = fmaxf(0.2f * f.w + m.w * inv, 0.f);
    } else {
        res = f;
    }
    ((float4*)out)[i] = res;
}

extern "C" void kernel_launch(void* const* d_in, const int* in_sizes, int n_in,
                              void* d_out, int out_size, void* d_ws, size_t ws_size,
                              hipStream_t stream) {
    const float* feat = (const float*)d_in[0];   // [N, 64]
    const float* W    = (const float*)d_in[1];   // [8, 64, 64]
    const int*   src  = (const int*)d_in[2];     // [E]
    const int*   dst  = (const int*)d_in[3];     // [E]
    const int*   et   = (const int*)d_in[4];     // [E]
    float* out = (float*)d_out;                  // [N, 64]

    const int N = N_NODES, E = N_EDGES;

    // Workspace layout (CSR path):
    char* p = (char*)d_ws;
    int* cnt = (int*)p;               p += align256((size_t)N * 4);
    int* off = (int*)p;               p += align256((size_t)(N + 1) * 4);
    int* cur = (int*)p;               p += align256((size_t)N * 4);
    int* eid = (int*)p;               p += align256((size_t)E * 4);
    float* hw = (float*)p;            p += (size_t)NRELS * N * FEAT * 4;
    size_t need_full = (size_t)(p - (char*)d_ws);

    // Old-path layout: [deg float N][hw]
    size_t need_old = align256((size_t)N * 4) + (size_t)NRELS * N * FEAT * 4;

    if (ws_size >= need_full) {
        hipMemsetAsync(cnt, 0, (size_t)N * 4, stream);
        hist_kernel<<<(E + 255) / 256, 256, 0, stream>>>(dst, cnt, E);
        scan_kernel<<<1, 1024, 0, stream>>>(cnt, off, cur, N);
        fill_kernel<<<(E + 255) / 256, 256, 0, stream>>>(dst, cur, eid, E);
        hw_kernel<<<dim3((N + 63) / 64, NRELS), 256, 0, stream>>>(feat, W, hw, N);
        reduce_kernel<<<(N + 3) / 4, 256, 0, stream>>>(off, eid, src, et, hw, feat, out, N);
    } else {
        float* deg = (float*)d_ws;
        float* hwo = (float*)((char*)d_ws + align256((size_t)N * 4));
        hipMemsetAsync(out, 0, (size_t)N * FEAT * 4, stream);
        hipMemsetAsync(deg, 0, (size_t)N * 4, stream);
        degf_kernel<<<(E + 255) / 256, 256, 0, stream>>>(dst, deg, E);
        if (ws_size >= need_old) {
            hw_kernel<<<dim3((N + 63) / 64, NRELS), 256, 0, stream>>>(feat, W, hwo, N);
            scatter_kernel<<<((size_t)E * 16 + 255) / 256, 256, 0, stream>>>(src, dst, et, hwo, out, E, N);
        } else {
            otf_kernel<<<(E + 3) / 4, 256, 0, stream>>>(src, dst, et, feat, W, out, E);
        }
        final_kernel<<<(N * 16 + 255) / 256, 256, 0, stream>>>(feat, deg, out, N);
    }
}

// Round 3
// 301.589 us; speedup vs baseline: 2.9704x; 1.4200x over previous
//
#include <hip/hip_runtime.h>
#include <hip/hip_bf16.h>

#define N_NODES 50000
#define N_EDGES 800000
#define FEAT 64
#define NRELS 8
#define SCAN_CHUNK 1024   // elements per scanA block (256 threads x int4)

static __host__ __device__ inline size_t align256(size_t x) { return (x + 255) & ~(size_t)255; }

// ---------------------------------------------------------------------------
// Kernel 1: int histogram of dst -> cnt (in-degree)
// ---------------------------------------------------------------------------
__global__ void hist_kernel(const int* __restrict__ dst, int* __restrict__ cnt, int E) {
    int e = blockIdx.x * blockDim.x + threadIdx.x;
    if (e < E) atomicAdd(cnt + dst[e], 1);
}

// ---------------------------------------------------------------------------
// Scan phase A: block-local exclusive scan of cnt -> off (local), totals -> part
// 256 threads x int4 = 1024 elements per block.
// ---------------------------------------------------------------------------
__global__ void scanA_kernel(const int* __restrict__ cnt, int* __restrict__ off,
                             int* __restrict__ part, int N) {
    __shared__ int sums[256];
    const int t = threadIdx.x;
    const int base = blockIdx.x * SCAN_CHUNK + t * 4;
    int4 v = make_int4(0, 0, 0, 0);
    if (base + 3 < N) {
        v = *(const int4*)(cnt + base);
    } else {
        if (base + 0 < N) v.x = cnt[base + 0];
        if (base + 1 < N) v.y = cnt[base + 1];
        if (base + 2 < N) v.z = cnt[base + 2];
        if (base + 3 < N) v.w = cnt[base + 3];
    }
    const int s = v.x + v.y + v.z + v.w;
    sums[t] = s;
    __syncthreads();
    for (int o = 1; o < 256; o <<= 1) {
        int u = (t >= o) ? sums[t - o] : 0;
        __syncthreads();
        sums[t] += u;
        __syncthreads();
    }
    const int ex = sums[t] - s;  // exclusive prefix of this thread within block
    int4 w;
    w.x = ex;
    w.y = ex + v.x;
    w.z = w.y + v.y;
    w.w = w.z + v.z;
    if (base + 3 < N) {
        *(int4*)(off + base) = w;
    } else {
        if (base + 0 < N) off[base + 0] = w.x;
        if (base + 1 < N) off[base + 1] = w.y;
        if (base + 2 < N) off[base + 2] = w.z;
        if (base + 3 < N) off[base + 3] = w.w;
    }
    if (t == 255) part[blockIdx.x] = sums[255];
}

// ---------------------------------------------------------------------------
// Scan phase B: one wave scans <=64 block partials in-place (exclusive),
// total stored at part[NB].
// ---------------------------------------------------------------------------
__global__ void scanB_kernel(int* __restrict__ part, int NB) {
    const int t = threadIdx.x;  // 64 threads
    int orig = (t < NB) ? part[t] : 0;
    int v = orig;
    for (int o = 1; o < 64; o <<= 1) {
        int u = __shfl_up(v, o);
        if (t >= o) v += u;
    }
    if (t < NB) part[t] = v - orig;  // exclusive
    if (t == 63) part[NB] = v;       // grand total
}

// ---------------------------------------------------------------------------
// Scan phase C: off[i] += part[i / SCAN_CHUNK]; cur[i] = off[i]; off[N] = total.
// int4 vectorized (N divisible by 4).
// ---------------------------------------------------------------------------
__global__ void scanC_kernel(int* __restrict__ off, int* __restrict__ cur,
                             const int* __restrict__ part, int N, int NB) {
    const int i = blockIdx.x * blockDim.x + threadIdx.x;  // over N/4 int4s
    const int n4 = N >> 2;
    if (i >= n4) return;
    const int p = part[i >> 8];   // (i*4) >> 10
    int4 v = *(const int4*)(off + i * 4);
    v.x += p; v.y += p; v.z += p; v.w += p;
    *(int4*)(off + i * 4) = v;
    *(int4*)(cur + i * 4) = v;
    if (i == 0) off[N] = part[NB];
}

// ---------------------------------------------------------------------------
// Kernel 3: CSR fill (counting-sort scatter of edge ids)
// ---------------------------------------------------------------------------
__global__ void fill_kernel(const int* __restrict__ dst, int* __restrict__ cur,
                            int* __restrict__ eid, int E) {
    int e = blockIdx.x * blockDim.x + threadIdx.x;
    if (e < E) {
        int pos = atomicAdd(cur + dst[e], 1);
        eid[pos] = e;
    }
}

// ---------------------------------------------------------------------------
// Kernel 4: hw[r][n][f] = sum_d feat[n][d] * W[r][d][f]
// ---------------------------------------------------------------------------
__global__ void hw_kernel(const float* __restrict__ feat, const float* __restrict__ W,
                          float* __restrict__ hw, int N) {
    __shared__ float Wl[64 * 64];      // [d][f]
    __shared__ float Fl[64 * 65];      // [n][d], +1 pad
    const int r  = blockIdx.y;
    const int n0 = blockIdx.x * 64;
    const int t  = threadIdx.x;

    const float4* W4  = (const float4*)(W + (size_t)r * 4096);
    float4*       Wl4 = (float4*)Wl;
#pragma unroll
    for (int i = 0; i < 4; i++) Wl4[t + 256 * i] = W4[t + 256 * i];

#pragma unroll
    for (int i = 0; i < 16; i++) {
        int idx = t + 256 * i;
        int n = idx >> 6, d = idx & 63;
        int gn = n0 + n;
        Fl[n * 65 + d] = (gn < N) ? feat[(size_t)gn * 64 + d] : 0.0f;
    }
    __syncthreads();

    const int q  = t & 15;
    const int nl = t >> 4;
#pragma unroll
    for (int pass = 0; pass < 4; pass++) {
        int n = nl + pass * 16;
        float4 acc = make_float4(0.f, 0.f, 0.f, 0.f);
#pragma unroll
        for (int d = 0; d < 64; d++) {
            float  fv = Fl[n * 65 + d];
            float4 wv = Wl4[d * 16 + q];
            acc.x += fv * wv.x; acc.y += fv * wv.y;
            acc.z += fv * wv.z; acc.w += fv * wv.w;
        }
        int gn = n0 + n;
        if (gn < N)
            ((float4*)hw)[((size_t)r * N + gn) * 16 + q] = acc;
    }
}

// ---------------------------------------------------------------------------
// Kernel 5: fused gather-reduce + epilogue. One wave per dst node.
// ---------------------------------------------------------------------------
__global__ void reduce_kernel(const int* __restrict__ off, const int* __restrict__ eid,
                              const int* __restrict__ src, const int* __restrict__ et,
                              const float* __restrict__ hw, const float* __restrict__ feat,
                              float* __restrict__ out, int N) {
    const int node = blockIdx.x * 4 + (threadIdx.x >> 6);
    if (node >= N) return;
    const int lane = threadIdx.x & 63;
    const int g = lane >> 4, q = lane & 15;

    const int b = off[node], e = off[node + 1];
    const int deg = e - b;

    float ax = 0.f, ay = 0.f, az = 0.f, aw = 0.f;
    for (int i = b + g; i < e; i += 4) {
        int edge = eid[i];
        int s = src[edge], r = et[edge];
        float4 v = ((const float4*)hw)[((size_t)r * N + s) * 16 + q];
        ax += v.x; ay += v.y; az += v.z; aw += v.w;
    }
    ax += __shfl_xor(ax, 16); ay += __shfl_xor(ay, 16);
    az += __shfl_xor(az, 16); aw += __shfl_xor(aw, 16);
    ax += __shfl_xor(ax, 32); ay += __shfl_xor(ay, 32);
    az += __shfl_xor(az, 32); aw += __shfl_xor(aw, 32);

    float4 f = ((const float4*)feat)[(size_t)node * 16 + q];
    float4 res;
    if (deg > 0) {
        float inv = 0.8f / (float)deg;
        res.x = fmaxf(0.2f * f.x + ax * inv, 0.f);
        res.y = fmaxf(0.2f * f.y + ay * inv, 0.f);
        res.z = fmaxf(0.2f * f.z + az * inv, 0.f);
        res.w = fmaxf(0.2f * f.w + aw * inv, 0.f);
    } else {
        res = f;
    }
    if (g == 0)
        ((float4*)out)[(size_t)node * 16 + q] = res;
}

// ---------------------------------------------------------------------------
// Fallback kernels (small workspace): R0 atomic-scatter path
// ---------------------------------------------------------------------------
__global__ void degf_kernel(const int* __restrict__ dst, float* __restrict__ deg, int E) {
    int e = blockIdx.x * blockDim.x + threadIdx.x;
    if (e < E) atomicAdd(deg + dst[e], 1.0f);
}

__global__ void otf_kernel(const int* __restrict__ src, const int* __restrict__ dst,
                           const int* __restrict__ et, const float* __restrict__ feat,
                           const float* __restrict__ W, float* __restrict__ out, int E) {
    int wid = (blockIdx.x * blockDim.x + threadIdx.x) >> 6;
    int l = threadIdx.x & 63;
    if (wid >= E) return;
    int s = src[wid], dd = dst[wid], r = et[wid];
    float fv = feat[(size_t)s * 64 + l];
    const float* Wr = W + (size_t)r * 4096;
    float acc = 0.f;
#pragma unroll
    for (int d = 0; d < 64; d++) {
        float a = __shfl(fv, d);
        acc += a * Wr[d * 64 + l];
    }
    atomicAdd(out + (size_t)dd * 64 + l, acc);
}

__global__ void final_kernel(const float* __restrict__ feat, const float* __restrict__ deg,
                             float* __restrict__ out, int N) {
    int i = blockIdx.x * blockDim.x + threadIdx.x;
    if (i >= N * 16) return;
    int n = i >> 4;
    float d = deg[n];
    float4 f = ((const float4*)feat)[i];
    float4 m = ((float4*)out)[i];
    float4 res;
    if (d > 0.f) {
        float inv = 0.8f / d;
        res.x = fmaxf(0.2f * f.x + m.x * inv, 0.f);
        res.y = fmaxf(0.2f * f.y + m.y * inv, 0.f);
        res.z = fmaxf(0.2f * f.z + m.z * inv, 0.f);
        res.w = fmaxf(0.2f * f.w + m.w * inv, 0.f);
    } else {
        res = f;
    }
    ((float4*)out)[i] = res;
}

extern "C" void kernel_launch(void* const* d_in, const int* in_sizes, int n_in,
                              void* d_out, int out_size, void* d_ws, size_t ws_size,
                              hipStream_t stream) {
    const float* feat = (const float*)d_in[0];   // [N, 64]
    const float* W    = (const float*)d_in[1];   // [8, 64, 64]
    const int*   src  = (const int*)d_in[2];     // [E]
    const int*   dst  = (const int*)d_in[3];     // [E]
    const int*   et   = (const int*)d_in[4];     // [E]
    float* out = (float*)d_out;                  // [N, 64]

    const int N = N_NODES, E = N_EDGES;
    const int NB = (N + SCAN_CHUNK - 1) / SCAN_CHUNK;   // 49

    // Workspace layout (CSR path):
    char* p = (char*)d_ws;
    int* cnt  = (int*)p;  p += align256((size_t)N * 4);
    int* off  = (int*)p;  p += align256((size_t)(N + 1) * 4);
    int* cur  = (int*)p;  p += align256((size_t)N * 4);
    int* part = (int*)p;  p += align256((size_t)(NB + 1) * 4);
    int* eid  = (int*)p;  p += align256((size_t)E * 4);
    float* hw = (float*)p; p += (size_t)NRELS * N * FEAT * 4;
    size_t need_full = (size_t)(p - (char*)d_ws);

    if (ws_size >= need_full) {
        hipMemsetAsync(cnt, 0, (size_t)N * 4, stream);
        hist_kernel<<<(E + 255) / 256, 256, 0, stream>>>(dst, cnt, E);
        scanA_kernel<<<NB, 256, 0, stream>>>(cnt, off, part, N);
        scanB_kernel<<<1, 64, 0, stream>>>(part, NB);
        scanC_kernel<<<((N >> 2) + 255) / 256, 256, 0, stream>>>(off, cur, part, N, NB);
        fill_kernel<<<(E + 255) / 256, 256, 0, stream>>>(dst, cur, eid, E);
        hw_kernel<<<dim3((N + 63) / 64, NRELS), 256, 0, stream>>>(feat, W, hw, N);
        reduce_kernel<<<(N + 3) / 4, 256, 0, stream>>>(off, eid, src, et, hw, feat, out, N);
    } else {
        // Minimal-workspace fallback: on-the-fly transform + atomics.
        float* deg = (float*)d_ws;
        hipMemsetAsync(out, 0, (size_t)N * FEAT * 4, stream);
        hipMemsetAsync(deg, 0, (size_t)N * 4, stream);
        degf_kernel<<<(E + 255) / 256, 256, 0, stream>>>(dst, deg, E);
        otf_kernel<<<(E + 3) / 4, 256, 0, stream>>>(src, dst, et, feat, W, out, E);
        final_kernel<<<(N * 16 + 255) / 256, 256, 0, stream>>>(feat, deg, out, N);
    }
}

// Round 4
// 243.384 us; speedup vs baseline: 3.6808x; 1.2391x over previous
//
#include <hip/hip_runtime.h>
#include <hip/hip_bf16.h>

#define N_NODES 50000
#define N_EDGES 800000
#define FEAT 64
#define NRELS 8
#define SCAN_CHUNK 1024   // elements per scanA block (256 threads x int4)

typedef __attribute__((ext_vector_type(8))) short bf16x8;   // 8 bf16 in 4 VGPRs
typedef __attribute__((ext_vector_type(4))) float f32x4;

static __host__ __device__ inline size_t align256(size_t x) { return (x + 255) & ~(size_t)255; }

__device__ inline unsigned short f2b(float f) {   // fp32 -> bf16 RNE
    unsigned u = __builtin_bit_cast(unsigned, f);
    unsigned r = (u + 0x7fffu + ((u >> 16) & 1u)) >> 16;
    return (unsigned short)r;
}
__device__ inline float b2f(unsigned short u) {   // bf16 -> fp32
    unsigned v = ((unsigned)u) << 16;
    return __builtin_bit_cast(float, v);
}

// ---------------------------------------------------------------------------
// Kernel 1: int histogram of dst -> cnt (in-degree)
// ---------------------------------------------------------------------------
__global__ void hist_kernel(const int* __restrict__ dst, int* __restrict__ cnt, int E) {
    int e = blockIdx.x * blockDim.x + threadIdx.x;
    if (e < E) atomicAdd(cnt + dst[e], 1);
}

// ---------------------------------------------------------------------------
// Scan phase A: block-local exclusive scan of cnt -> off, totals -> part
// ---------------------------------------------------------------------------
__global__ void scanA_kernel(const int* __restrict__ cnt, int* __restrict__ off,
                             int* __restrict__ part, int N) {
    __shared__ int sums[256];
    const int t = threadIdx.x;
    const int base = blockIdx.x * SCAN_CHUNK + t * 4;
    int4 v = make_int4(0, 0, 0, 0);
    if (base + 3 < N) {
        v = *(const int4*)(cnt + base);
    } else {
        if (base + 0 < N) v.x = cnt[base + 0];
        if (base + 1 < N) v.y = cnt[base + 1];
        if (base + 2 < N) v.z = cnt[base + 2];
        if (base + 3 < N) v.w = cnt[base + 3];
    }
    const int s = v.x + v.y + v.z + v.w;
    sums[t] = s;
    __syncthreads();
    for (int o = 1; o < 256; o <<= 1) {
        int u = (t >= o) ? sums[t - o] : 0;
        __syncthreads();
        sums[t] += u;
        __syncthreads();
    }
    const int ex = sums[t] - s;
    int4 w;
    w.x = ex;
    w.y = ex + v.x;
    w.z = w.y + v.y;
    w.w = w.z + v.z;
    if (base + 3 < N) {
        *(int4*)(off + base) = w;
    } else {
        if (base + 0 < N) off[base + 0] = w.x;
        if (base + 1 < N) off[base + 1] = w.y;
        if (base + 2 < N) off[base + 2] = w.z;
        if (base + 3 < N) off[base + 3] = w.w;
    }
    if (t == 255) part[blockIdx.x] = sums[255];
}

// ---------------------------------------------------------------------------
// Scan phase B: one wave scans <=64 block partials (exclusive), total at part[NB].
// ---------------------------------------------------------------------------
__global__ void scanB_kernel(int* __restrict__ part, int NB) {
    const int t = threadIdx.x;  // 64 threads
    int orig = (t < NB) ? part[t] : 0;
    int v = orig;
    for (int o = 1; o < 64; o <<= 1) {
        int u = __shfl_up(v, o);
        if (t >= o) v += u;
    }
    if (t < NB) part[t] = v - orig;
    if (t == 63) part[NB] = v;
}

// ---------------------------------------------------------------------------
// Scan phase C: off[i] += part[i / SCAN_CHUNK]; cur = off; off[N] = total.
// ---------------------------------------------------------------------------
__global__ void scanC_kernel(int* __restrict__ off, int* __restrict__ cur,
                             const int* __restrict__ part, int N, int NB) {
    const int i = blockIdx.x * blockDim.x + threadIdx.x;
    const int n4 = N >> 2;
    if (i >= n4) return;
    const int p = part[i >> 8];
    int4 v = *(const int4*)(off + i * 4);
    v.x += p; v.y += p; v.z += p; v.w += p;
    *(int4*)(off + i * 4) = v;
    *(int4*)(cur + i * 4) = v;
    if (i == 0) off[N] = part[NB];
}

// ---------------------------------------------------------------------------
// Kernel 3: CSR fill (counting-sort scatter of edge ids)
// ---------------------------------------------------------------------------
__global__ void fill_kernel(const int* __restrict__ dst, int* __restrict__ cur,
                            int* __restrict__ eid, int E) {
    int e = blockIdx.x * blockDim.x + threadIdx.x;
    if (e < E) {
        int pos = atomicAdd(cur + dst[e], 1);
        eid[pos] = e;
    }
}

// ---------------------------------------------------------------------------
// Kernel 4: hwb[r][n][f] (bf16) = feat[n,:] @ W[r]  via bf16 MFMA 16x16x32.
// Block = 256 threads (4 waves) computes 64 nodes x 64 f for one relation.
// LDS: feat tile + W^T tile as bf16, row stride 72 (144B = 9*16B, b128-aligned).
// Wave w handles nodes [w*16, w*16+16); 4 f-tiles x 2 K-steps = 8 MFMAs.
// ---------------------------------------------------------------------------
__global__ void hwb_kernel(const float* __restrict__ feat, const float* __restrict__ W,
                           unsigned short* __restrict__ hwb, int N) {
    __shared__ unsigned short Fl[64 * 72];   // [node][d]
    __shared__ unsigned short Wt[64 * 72];   // [f][d]  (W transposed)
    const int r  = blockIdx.y;
    const int n0 = blockIdx.x * 64;
    const int t  = threadIdx.x;

    // Stage feat tile: 1024 float4s, 4 per thread -> bf16, contiguous d runs.
    const float4* F4 = (const float4*)feat;
#pragma unroll
    for (int i = 0; i < 4; i++) {
        int idx = t + 256 * i;            // [0,1024)
        int n = idx >> 4;                 // 16 float4 per node row
        int c = idx & 15;                 // float4 within row
        int gn = n0 + n;
        float4 v = make_float4(0.f, 0.f, 0.f, 0.f);
        if (gn < N) v = F4[(size_t)gn * 16 + c];
        ushort4 b;
        b.x = f2b(v.x); b.y = f2b(v.y); b.z = f2b(v.z); b.w = f2b(v.w);
        *(ushort4*)&Fl[n * 72 + c * 4] = b;
    }
    // Stage W_r transposed: thread loads float4 of W[d][f], writes Wt[f][d] scalar.
    const float4* W4 = (const float4*)(W + (size_t)r * 4096);
#pragma unroll
    for (int i = 0; i < 4; i++) {
        int idx = t + 256 * i;            // [0,1024)
        int d = idx >> 4;
        int f0 = (idx & 15) * 4;
        float4 v = W4[idx];
        Wt[(f0 + 0) * 72 + d] = f2b(v.x);
        Wt[(f0 + 1) * 72 + d] = f2b(v.y);
        Wt[(f0 + 2) * 72 + d] = f2b(v.z);
        Wt[(f0 + 3) * 72 + d] = f2b(v.w);
    }
    __syncthreads();

    const int w    = t >> 6;          // wave 0..3
    const int l    = t & 63;
    const int col  = l & 15;
    const int quad = l >> 4;

    // A fragments: A[m = col][k = quad*8 + j], two K-steps (k and k+32).
    const int arow = (w * 16 + col) * 72 + quad * 8;
    bf16x8 a0 = *(const bf16x8*)&Fl[arow];
    bf16x8 a1 = *(const bf16x8*)&Fl[arow + 32];

#pragma unroll
    for (int ft = 0; ft < 4; ft++) {
        const int brow = (ft * 16 + col) * 72 + quad * 8;
        bf16x8 b0 = *(const bf16x8*)&Wt[brow];
        bf16x8 b1 = *(const bf16x8*)&Wt[brow + 32];
        f32x4 acc = {0.f, 0.f, 0.f, 0.f};
        acc = __builtin_amdgcn_mfma_f32_16x16x32_bf16(a0, b0, acc, 0, 0, 0);
        acc = __builtin_amdgcn_mfma_f32_16x16x32_bf16(a1, b1, acc, 0, 0, 0);
        // D: node = n0 + w*16 + quad*4 + i, f = ft*16 + col
#pragma unroll
        for (int i = 0; i < 4; i++) {
            int gn = n0 + w * 16 + quad * 4 + i;
            if (gn < N)
                hwb[((size_t)r * N + gn) * 64 + ft * 16 + col] = f2b(acc[i]);
        }
    }
}

// ---------------------------------------------------------------------------
// Kernel 5: fused gather-reduce + epilogue, bf16 hw. One wave per dst node.
// Lane: g = lane>>4 (4 edges in flight), q = lane&15 (4 feats each, ushort4).
// ---------------------------------------------------------------------------
__global__ void reduce_kernel(const int* __restrict__ off, const int* __restrict__ eid,
                              const int* __restrict__ src, const int* __restrict__ et,
                              const unsigned short* __restrict__ hwb,
                              const float* __restrict__ feat,
                              float* __restrict__ out, int N) {
    const int node = blockIdx.x * 4 + (threadIdx.x >> 6);
    if (node >= N) return;
    const int lane = threadIdx.x & 63;
    const int g = lane >> 4, q = lane & 15;

    const int b = off[node], e = off[node + 1];
    const int deg = e - b;

    float ax = 0.f, ay = 0.f, az = 0.f, aw = 0.f;
    for (int i = b + g; i < e; i += 4) {
        int edge = eid[i];
        int s = src[edge], r = et[edge];
        ushort4 u = *(const ushort4*)(hwb + ((size_t)r * N + s) * 64 + q * 4);
        ax += b2f(u.x); ay += b2f(u.y); az += b2f(u.z); aw += b2f(u.w);
    }
    ax += __shfl_xor(ax, 16); ay += __shfl_xor(ay, 16);
    az += __shfl_xor(az, 16); aw += __shfl_xor(aw, 16);
    ax += __shfl_xor(ax, 32); ay += __shfl_xor(ay, 32);
    az += __shfl_xor(az, 32); aw += __shfl_xor(aw, 32);

    float4 f = ((const float4*)feat)[(size_t)node * 16 + q];
    float4 res;
    if (deg > 0) {
        float inv = 0.8f / (float)deg;
        res.x = fmaxf(0.2f * f.x + ax * inv, 0.f);
        res.y = fmaxf(0.2f * f.y + ay * inv, 0.f);
        res.z = fmaxf(0.2f * f.z + az * inv, 0.f);
        res.w = fmaxf(0.2f * f.w + aw * inv, 0.f);
    } else {
        res = f;
    }
    if (g == 0)
        ((float4*)out)[(size_t)node * 16 + q] = res;
}

// ---------------------------------------------------------------------------
// Fallback kernels (small workspace): on-the-fly transform + atomics (fp32).
// ---------------------------------------------------------------------------
__global__ void degf_kernel(const int* __restrict__ dst, float* __restrict__ deg, int E) {
    int e = blockIdx.x * blockDim.x + threadIdx.x;
    if (e < E) atomicAdd(deg + dst[e], 1.0f);
}

__global__ void otf_kernel(const int* __restrict__ src, const int* __restrict__ dst,
                           const int* __restrict__ et, const float* __restrict__ feat,
                           const float* __restrict__ W, float* __restrict__ out, int E) {
    int wid = (blockIdx.x * blockDim.x + threadIdx.x) >> 6;
    int l = threadIdx.x & 63;
    if (wid >= E) return;
    int s = src[wid], dd = dst[wid], r = et[wid];
    float fv = feat[(size_t)s * 64 + l];
    const float* Wr = W + (size_t)r * 4096;
    float acc = 0.f;
#pragma unroll
    for (int d = 0; d < 64; d++) {
        float a = __shfl(fv, d);
        acc += a * Wr[d * 64 + l];
    }
    atomicAdd(out + (size_t)dd * 64 + l, acc);
}

__global__ void final_kernel(const float* __restrict__ feat, const float* __restrict__ deg,
                             float* __restrict__ out, int N) {
    int i = blockIdx.x * blockDim.x + threadIdx.x;
    if (i >= N * 16) return;
    int n = i >> 4;
    float d = deg[n];
    float4 f = ((const float4*)feat)[i];
    float4 m = ((float4*)out)[i];
    float4 res;
    if (d > 0.f) {
        float inv = 0.8f / d;
        res.x = fmaxf(0.2f * f.x + m.x * inv, 0.f);
        res.y = fmaxf(0.2f * f.y + m.y * inv, 0.f);
        res.z = fmaxf(0.2f * f.z + m.z * inv, 0.f);
        res.w = fmaxf(0.2f * f.w + m.w * inv, 0.f);
    } else {
        res = f;
    }
    ((float4*)out)[i] = res;
}

extern "C" void kernel_launch(void* const* d_in, const int* in_sizes, int n_in,
                              void* d_out, int out_size, void* d_ws, size_t ws_size,
                              hipStream_t stream) {
    const float* feat = (const float*)d_in[0];   // [N, 64]
    const float* W    = (const float*)d_in[1];   // [8, 64, 64]
    const int*   src  = (const int*)d_in[2];     // [E]
    const int*   dst  = (const int*)d_in[3];     // [E]
    const int*   et   = (const int*)d_in[4];     // [E]
    float* out = (float*)d_out;                  // [N, 64]

    const int N = N_NODES, E = N_EDGES;
    const int NB = (N + SCAN_CHUNK - 1) / SCAN_CHUNK;   // 49

    // Workspace layout (CSR path):
    char* p = (char*)d_ws;
    int* cnt  = (int*)p;  p += align256((size_t)N * 4);
    int* off  = (int*)p;  p += align256((size_t)(N + 1) * 4);
    int* cur  = (int*)p;  p += align256((size_t)N * 4);
    int* part = (int*)p;  p += align256((size_t)(NB + 1) * 4);
    int* eid  = (int*)p;  p += align256((size_t)E * 4);
    unsigned short* hwb = (unsigned short*)p;
    p += (size_t)NRELS * N * FEAT * 2;           // bf16 hw: 51.2 MB
    size_t need_full = (size_t)(p - (char*)d_ws);

    if (ws_size >= need_full) {
        hipMemsetAsync(cnt, 0, (size_t)N * 4, stream);
        hist_kernel<<<(E + 255) / 256, 256, 0, stream>>>(dst, cnt, E);
        scanA_kernel<<<NB, 256, 0, stream>>>(cnt, off, part, N);
        scanB_kernel<<<1, 64, 0, stream>>>(part, NB);
        scanC_kernel<<<((N >> 2) + 255) / 256, 256, 0, stream>>>(off, cur, part, N, NB);
        fill_kernel<<<(E + 255) / 256, 256, 0, stream>>>(dst, cur, eid, E);
        hwb_kernel<<<dim3((N + 63) / 64, NRELS), 256, 0, stream>>>(feat, W, hwb, N);
        reduce_kernel<<<(N + 3) / 4, 256, 0, stream>>>(off, eid, src, et, hwb, feat, out, N);
    } else {
        // Minimal-workspace fallback.
        float* deg = (float*)d_ws;
        hipMemsetAsync(out, 0, (size_t)N * FEAT * 4, stream);
        hipMemsetAsync(deg, 0, (size_t)N * 4, stream);
        degf_kernel<<<(E + 255) / 256, 256, 0, stream>>>(dst, deg, E);
        otf_kernel<<<(E + 3) / 4, 256, 0, stream>>>(src, dst, et, feat, W, out, E);
        final_kernel<<<(N * 16 + 255) / 256, 256, 0, stream>>>(feat, deg, out, N);
    }
}

// Round 5
// 194.317 us; speedup vs baseline: 4.6102x; 1.2525x over previous
//
#include <hip/hip_runtime.h>
#include <hip/hip_bf16.h>

#define N_NODES 50000
#define N_EDGES 800000
#define FEAT 64
#define NRELS 8
#define SCAN_CHUNK 1024   // elements per scanA block (256 threads x int4)
#define NBUCK 196         // ceil(50000/256) coarse buckets (dst >> 8)
#define EPB 2048          // edges per bfill block

typedef __attribute__((ext_vector_type(8))) short bf16x8;   // 8 bf16 in 4 VGPRs
typedef __attribute__((ext_vector_type(4))) float f32x4;

static __host__ __device__ inline size_t align256(size_t x) { return (x + 255) & ~(size_t)255; }

__device__ inline unsigned short f2b(float f) {   // fp32 -> bf16 RNE
    unsigned u = __builtin_bit_cast(unsigned, f);
    unsigned r = (u + 0x7fffu + ((u >> 16) & 1u)) >> 16;
    return (unsigned short)r;
}
__device__ inline float b2f(unsigned short u) {   // bf16 -> fp32
    unsigned v = ((unsigned)u) << 16;
    return __builtin_bit_cast(float, v);
}

// ---------------------------------------------------------------------------
// Kernel 1: int histogram of dst -> cnt (in-degree)
// ---------------------------------------------------------------------------
__global__ void hist_kernel(const int* __restrict__ dst, int* __restrict__ cnt, int E) {
    int e = blockIdx.x * blockDim.x + threadIdx.x;
    if (e < E) atomicAdd(cnt + dst[e], 1);
}

// ---------------------------------------------------------------------------
// Scan phase A: block-local exclusive scan of cnt -> off, totals -> part
// ---------------------------------------------------------------------------
__global__ void scanA_kernel(const int* __restrict__ cnt, int* __restrict__ off,
                             int* __restrict__ part, int N) {
    __shared__ int sums[256];
    const int t = threadIdx.x;
    const int base = blockIdx.x * SCAN_CHUNK + t * 4;
    int4 v = make_int4(0, 0, 0, 0);
    if (base + 3 < N) {
        v = *(const int4*)(cnt + base);
    } else {
        if (base + 0 < N) v.x = cnt[base + 0];
        if (base + 1 < N) v.y = cnt[base + 1];
        if (base + 2 < N) v.z = cnt[base + 2];
        if (base + 3 < N) v.w = cnt[base + 3];
    }
    const int s = v.x + v.y + v.z + v.w;
    sums[t] = s;
    __syncthreads();
    for (int o = 1; o < 256; o <<= 1) {
        int u = (t >= o) ? sums[t - o] : 0;
        __syncthreads();
        sums[t] += u;
        __syncthreads();
    }
    const int ex = sums[t] - s;
    int4 w;
    w.x = ex;
    w.y = ex + v.x;
    w.z = w.y + v.y;
    w.w = w.z + v.z;
    if (base + 3 < N) {
        *(int4*)(off + base) = w;
    } else {
        if (base + 0 < N) off[base + 0] = w.x;
        if (base + 1 < N) off[base + 1] = w.y;
        if (base + 2 < N) off[base + 2] = w.z;
        if (base + 3 < N) off[base + 3] = w.w;
    }
    if (t == 255) part[blockIdx.x] = sums[255];
}

// ---------------------------------------------------------------------------
// Scan phase B: one wave scans <=64 block partials (exclusive), total at part[NB].
// ---------------------------------------------------------------------------
__global__ void scanB_kernel(int* __restrict__ part, int NB) {
    const int t = threadIdx.x;  // 64 threads
    int orig = (t < NB) ? part[t] : 0;
    int v = orig;
    for (int o = 1; o < 64; o <<= 1) {
        int u = __shfl_up(v, o);
        if (t >= o) v += u;
    }
    if (t < NB) part[t] = v - orig;
    if (t == 63) part[NB] = v;
}

// ---------------------------------------------------------------------------
// Scan phase C: off[i] += part[i / SCAN_CHUNK]; off[N] = total;
// also emit bucket write-cursors bcur[b] = off[b*256].
// ---------------------------------------------------------------------------
__global__ void scanC_kernel(int* __restrict__ off, const int* __restrict__ part,
                             int* __restrict__ bcur, int N, int NB) {
    const int i = blockIdx.x * blockDim.x + threadIdx.x;  // over N/4 int4s
    const int n4 = N >> 2;
    if (i >= n4) return;
    const int p = part[i >> 8];
    int4 v = *(const int4*)(off + i * 4);
    v.x += p; v.y += p; v.z += p; v.w += p;
    *(int4*)(off + i * 4) = v;
    if ((i & 63) == 0) bcur[i >> 6] = v.x;   // node i*4 is multiple of 256
    if (i == 0) off[N] = part[NB];
}

// ---------------------------------------------------------------------------
// Kernel 3a: bucket fill. Each block bins EPB edges by coarse bucket (dst>>8)
// into per-(block,bucket) contiguous runs reserved with one global atomic per
// bucket. Entry = src | et<<16 | (dst&255)<<19. Dense-ish line writes.
// ---------------------------------------------------------------------------
__global__ void bfill_kernel(const int* __restrict__ dst, const int* __restrict__ srcv,
                             const int* __restrict__ et, int* __restrict__ bcur,
                             int* __restrict__ tmp, int E) {
    __shared__ int hist[256];
    __shared__ int base[256];
    __shared__ int lcur[256];
    const int t = threadIdx.x;
    hist[t] = 0; lcur[t] = 0;
    __syncthreads();
    const int e0 = blockIdx.x * EPB;
    int bk[8], pk[8];
#pragma unroll
    for (int k = 0; k < 8; k++) {
        int e = e0 + t + k * 256;
        if (e < E) {
            int dd = dst[e];
            bk[k] = dd >> 8;
            pk[k] = (srcv[e] & 0xFFFF) | (et[e] << 16) | ((dd & 255) << 19);
            atomicAdd(&hist[bk[k]], 1);
        } else bk[k] = -1;
    }
    __syncthreads();
    if (t < NBUCK && hist[t] > 0) base[t] = atomicAdd(&bcur[t], hist[t]);
    __syncthreads();
#pragma unroll
    for (int k = 0; k < 8; k++) {
        if (bk[k] >= 0) {
            int r = atomicAdd(&lcur[bk[k]], 1);
            tmp[base[bk[k]] + r] = pk[k];
        }
    }
}

// ---------------------------------------------------------------------------
// Kernel 3b: exact sort within bucket. One block per bucket; LDS cursors start
// at off[node]; scattered writes stay within the bucket's ~16KB CSR window.
// ---------------------------------------------------------------------------
__global__ void sort2_kernel(const int* __restrict__ off, const int* __restrict__ tmp,
                             int* __restrict__ spk, int N) {
    __shared__ int gcur[256];
    const int b = blockIdx.x;
    const int t = threadIdx.x;
    const int n0 = b * 256;
    const int nn = min(256, N - n0);
    if (t < nn) gcur[t] = off[n0 + t];
    __syncthreads();
    const int s0 = off[n0];
    const int s1 = off[(n0 + 256 < N) ? (n0 + 256) : N];
    for (int i = s0 + t; i < s1; i += 256) {
        int e = tmp[i];
        int dlo = (e >> 19) & 255;
        int pos = atomicAdd(&gcur[dlo], 1);
        spk[pos] = e;
    }
}

// ---------------------------------------------------------------------------
// Kernel 4: hwb[r][n][f] (bf16) = feat[n,:] @ W[r]  via bf16 MFMA 16x16x32.
// ---------------------------------------------------------------------------
__global__ void hwb_kernel(const float* __restrict__ feat, const float* __restrict__ W,
                           unsigned short* __restrict__ hwb, int N) {
    __shared__ unsigned short Fl[64 * 72];   // [node][d]
    __shared__ unsigned short Wt[64 * 72];   // [f][d]  (W transposed)
    const int r  = blockIdx.y;
    const int n0 = blockIdx.x * 64;
    const int t  = threadIdx.x;

    const float4* F4 = (const float4*)feat;
#pragma unroll
    for (int i = 0; i < 4; i++) {
        int idx = t + 256 * i;            // [0,1024)
        int n = idx >> 4;
        int c = idx & 15;
        int gn = n0 + n;
        float4 v = make_float4(0.f, 0.f, 0.f, 0.f);
        if (gn < N) v = F4[(size_t)gn * 16 + c];
        ushort4 b;
        b.x = f2b(v.x); b.y = f2b(v.y); b.z = f2b(v.z); b.w = f2b(v.w);
        *(ushort4*)&Fl[n * 72 + c * 4] = b;
    }
    const float4* W4 = (const float4*)(W + (size_t)r * 4096);
#pragma unroll
    for (int i = 0; i < 4; i++) {
        int idx = t + 256 * i;
        int d = idx >> 4;
        int f0 = (idx & 15) * 4;
        float4 v = W4[idx];
        Wt[(f0 + 0) * 72 + d] = f2b(v.x);
        Wt[(f0 + 1) * 72 + d] = f2b(v.y);
        Wt[(f0 + 2) * 72 + d] = f2b(v.z);
        Wt[(f0 + 3) * 72 + d] = f2b(v.w);
    }
    __syncthreads();

    const int w    = t >> 6;
    const int l    = t & 63;
    const int col  = l & 15;
    const int quad = l >> 4;

    const int arow = (w * 16 + col) * 72 + quad * 8;
    bf16x8 a0 = *(const bf16x8*)&Fl[arow];
    bf16x8 a1 = *(const bf16x8*)&Fl[arow + 32];

#pragma unroll
    for (int ft = 0; ft < 4; ft++) {
        const int brow = (ft * 16 + col) * 72 + quad * 8;
        bf16x8 b0 = *(const bf16x8*)&Wt[brow];
        bf16x8 b1 = *(const bf16x8*)&Wt[brow + 32];
        f32x4 acc = {0.f, 0.f, 0.f, 0.f};
        acc = __builtin_amdgcn_mfma_f32_16x16x32_bf16(a0, b0, acc, 0, 0, 0);
        acc = __builtin_amdgcn_mfma_f32_16x16x32_bf16(a1, b1, acc, 0, 0, 0);
#pragma unroll
        for (int i = 0; i < 4; i++) {
            int gn = n0 + w * 16 + quad * 4 + i;
            if (gn < N)
                hwb[((size_t)r * N + gn) * 64 + ft * 16 + col] = f2b(acc[i]);
        }
    }
}

// ---------------------------------------------------------------------------
// Kernel 5: fused gather-reduce + epilogue, packed sorted edges. One wave per
// dst node. Lane: g = lane>>4 (4 edges in flight), q = lane&15 (ushort4 slice).
// ---------------------------------------------------------------------------
__global__ void reduce_kernel(const int* __restrict__ off, const int* __restrict__ spk,
                              const unsigned short* __restrict__ hwb,
                              const float* __restrict__ feat,
                              float* __restrict__ out, int N) {
    const int node = blockIdx.x * 4 + (threadIdx.x >> 6);
    if (node >= N) return;
    const int lane = threadIdx.x & 63;
    const int g = lane >> 4, q = lane & 15;

    const int b = off[node], e = off[node + 1];
    const int deg = e - b;

    float ax = 0.f, ay = 0.f, az = 0.f, aw = 0.f;
    for (int i = b + g; i < e; i += 4) {
        int pk = spk[i];
        int s = pk & 0xFFFF, r = (pk >> 16) & 7;
        ushort4 u = *(const ushort4*)(hwb + ((size_t)r * N + s) * 64 + q * 4);
        ax += b2f(u.x); ay += b2f(u.y); az += b2f(u.z); aw += b2f(u.w);
    }
    ax += __shfl_xor(ax, 16); ay += __shfl_xor(ay, 16);
    az += __shfl_xor(az, 16); aw += __shfl_xor(aw, 16);
    ax += __shfl_xor(ax, 32); ay += __shfl_xor(ay, 32);
    az += __shfl_xor(az, 32); aw += __shfl_xor(aw, 32);

    float4 f = ((const float4*)feat)[(size_t)node * 16 + q];
    float4 res;
    if (deg > 0) {
        float inv = 0.8f / (float)deg;
        res.x = fmaxf(0.2f * f.x + ax * inv, 0.f);
        res.y = fmaxf(0.2f * f.y + ay * inv, 0.f);
        res.z = fmaxf(0.2f * f.z + az * inv, 0.f);
        res.w = fmaxf(0.2f * f.w + aw * inv, 0.f);
    } else {
        res = f;
    }
    if (g == 0)
        ((float4*)out)[(size_t)node * 16 + q] = res;
}

// ---------------------------------------------------------------------------
// Fallback kernels (small workspace): on-the-fly transform + atomics (fp32).
// ---------------------------------------------------------------------------
__global__ void degf_kernel(const int* __restrict__ dst, float* __restrict__ deg, int E) {
    int e = blockIdx.x * blockDim.x + threadIdx.x;
    if (e < E) atomicAdd(deg + dst[e], 1.0f);
}

__global__ void otf_kernel(const int* __restrict__ src, const int* __restrict__ dst,
                           const int* __restrict__ et, const float* __restrict__ feat,
                           const float* __restrict__ W, float* __restrict__ out, int E) {
    int wid = (blockIdx.x * blockDim.x + threadIdx.x) >> 6;
    int l = threadIdx.x & 63;
    if (wid >= E) return;
    int s = src[wid], dd = dst[wid], r = et[wid];
    float fv = feat[(size_t)s * 64 + l];
    const float* Wr = W + (size_t)r * 4096;
    float acc = 0.f;
#pragma unroll
    for (int d = 0; d < 64; d++) {
        float a = __shfl(fv, d);
        acc += a * Wr[d * 64 + l];
    }
    atomicAdd(out + (size_t)dd * 64 + l, acc);
}

__global__ void final_kernel(const float* __restrict__ feat, const float* __restrict__ deg,
                             float* __restrict__ out, int N) {
    int i = blockIdx.x * blockDim.x + threadIdx.x;
    if (i >= N * 16) return;
    int n = i >> 4;
    float d = deg[n];
    float4 f = ((const float4*)feat)[i];
    float4 m = ((float4*)out)[i];
    float4 res;
    if (d > 0.f) {
        float inv = 0.8f / d;
        res.x = fmaxf(0.2f * f.x + m.x * inv, 0.f);
        res.y = fmaxf(0.2f * f.y + m.y * inv, 0.f);
        res.z = fmaxf(0.2f * f.z + m.z * inv, 0.f);
        res.w = fmaxf(0.2f * f.w + m.w * inv, 0.f);
    } else {
        res = f;
    }
    ((float4*)out)[i] = res;
}

extern "C" void kernel_launch(void* const* d_in, const int* in_sizes, int n_in,
                              void* d_out, int out_size, void* d_ws, size_t ws_size,
                              hipStream_t stream) {
    const float* feat = (const float*)d_in[0];   // [N, 64]
    const float* W    = (const float*)d_in[1];   // [8, 64, 64]
    const int*   src  = (const int*)d_in[2];     // [E]
    const int*   dst  = (const int*)d_in[3];     // [E]
    const int*   et   = (const int*)d_in[4];     // [E]
    float* out = (float*)d_out;                  // [N, 64]

    const int N = N_NODES, E = N_EDGES;
    const int NB = (N + SCAN_CHUNK - 1) / SCAN_CHUNK;   // 49

    // Workspace layout (CSR path):
    char* p = (char*)d_ws;
    int* cnt  = (int*)p;  p += align256((size_t)N * 4);
    int* off  = (int*)p;  p += align256((size_t)(N + 1) * 4);
    int* part = (int*)p;  p += align256((size_t)(NB + 1) * 4);
    int* bcur = (int*)p;  p += align256((size_t)256 * 4);
    int* tmp  = (int*)p;  p += align256((size_t)E * 4);
    int* spk  = (int*)p;  p += align256((size_t)E * 4);
    unsigned short* hwb = (unsigned short*)p;
    p += (size_t)NRELS * N * FEAT * 2;           // bf16 hw: 51.2 MB
    size_t need_full = (size_t)(p - (char*)d_ws);

    if (ws_size >= need_full) {
        hipMemsetAsync(cnt, 0, (size_t)N * 4, stream);
        hist_kernel<<<(E + 255) / 256, 256, 0, stream>>>(dst, cnt, E);
        scanA_kernel<<<NB, 256, 0, stream>>>(cnt, off, part, N);
        scanB_kernel<<<1, 64, 0, stream>>>(part, NB);
        scanC_kernel<<<((N >> 2) + 255) / 256, 256, 0, stream>>>(off, part, bcur, N, NB);
        bfill_kernel<<<(E + EPB - 1) / EPB, 256, 0, stream>>>(dst, src, et, bcur, tmp, E);
        sort2_kernel<<<NBUCK, 256, 0, stream>>>(off, tmp, spk, N);
        hwb_kernel<<<dim3((N + 63) / 64, NRELS), 256, 0, stream>>>(feat, W, hwb, N);
        reduce_kernel<<<(N + 3) / 4, 256, 0, stream>>>(off, spk, hwb, feat, out, N);
    } else {
        // Minimal-workspace fallback.
        float* deg = (float*)d_ws;
        hipMemsetAsync(out, 0, (size_t)N * FEAT * 4, stream);
        hipMemsetAsync(deg, 0, (size_t)N * 4, stream);
        degf_kernel<<<(E + 255) / 256, 256, 0, stream>>>(dst, deg, E);
        otf_kernel<<<(E + 3) / 4, 256, 0, stream>>>(src, dst, et, feat, W, out, E);
        final_kernel<<<(N * 16 + 255) / 256, 256, 0, stream>>>(feat, deg, out, N);
    }
}